// Round 10
// baseline (170.345 us; speedup 1.0000x reference)
//
#include <hip/hip_runtime.h>
#include <hip/hip_fp16.h>

#define NF 64
#define OCAP 65536

// ---------------- fp16 copy of x ----------------
__global__ __launch_bounds__(256) void k_half(const float* __restrict__ x,
                                              __half* __restrict__ xh, int total4) {
    int i = blockIdx.x * 256 + threadIdx.x;
    if (i >= total4) return;
    float4 v = reinterpret_cast<const float4*>(x)[i];
    __half2 p0 = __floats2half2_rn(v.x, v.y);
    __half2 p1 = __floats2half2_rn(v.z, v.w);
    uint2 u;
    u.x = *reinterpret_cast<unsigned*>(&p0);
    u.y = *reinterpret_cast<unsigned*>(&p1);
    reinterpret_cast<uint2*>(xh)[i] = u;
}

// ---------------- single-pass ELL build (ELL inside d_out), XCD-windowed ----------------
// out row d (64 floats) = node d's 64 int slots. Group blockIdx%8 handles only
// dst window g -> all writes to a line come from one XCD's L2, written back once.

__global__ __launch_bounds__(256) void k_ell(const int* __restrict__ src,
                                             const int* __restrict__ dst,
                                             int* degc, int* ocnt, int* oflow,
                                             int* ell, int e, int n) {
    int grp = blockIdx.x & 7;
    int chunk = (n + 7) >> 3;
    int lo = grp * chunk;
    int hi = min(lo + chunk, n);
    int nb = gridDim.x >> 3;
    int bi = blockIdx.x >> 3;
    for (int i = bi * 256 + threadIdx.x; i < e; i += nb * 256) {
        int d = dst[i];
        if (d < lo || d >= hi) continue;
        int s = src[i];
        int slot = atomicAdd(&degc[d], 1);
        if (slot < NF) {
            ell[(unsigned)d * NF + slot] = s;
        } else {                                   // P(deg>64)~0; correctness fallback
            int o = atomicAdd(ocnt, 1);
            if (o < OCAP) { oflow[2 * o] = s; oflow[2 * o + 1] = d; }
        }
    }
}

__global__ __launch_bounds__(256) void k_dinv(const int* __restrict__ degc,
                                              float* __restrict__ dinv, int n) {
    int i = blockIdx.x * 256 + threadIdx.x;
    if (i < n) dinv[i] = rsqrtf((float)(degc[i] + 1));   // +1 self-loop
}

// ---------------- fused gather-aggregate + GEMM epilogue ----------------
// 1 node/wave, lane = feature. ELL row read from out (full-wave 256B); per-slot
// weights gathered ONCE (wv = dinv[ev], lanes=slots) then distributed by shfl.
// Invalid slots pre-masked to ev=0,w=0 -> mask-free inner loop. fp16 x gather.
// No in-loop barriers (vsh wave-local). out row overwritten by same wave at end.

__global__ __launch_bounds__(256) void k_agg_gemm(const __half* __restrict__ xh,
                                                  const float* __restrict__ W,
                                                  const float* __restrict__ bias,
                                                  const float* __restrict__ dinv,
                                                  const int* __restrict__ degc,
                                                  float* out, int n) {
    __shared__ float wt[NF * NF];      // wt[k*64+j] = W[j][k]
    __shared__ float vsh[4][NF];
    int tid = threadIdx.x;
    for (int idx = tid; idx < NF * NF; idx += 256) {
        int k = idx >> 6, j = idx & 63;
        wt[idx] = W[j * NF + k];
    }
    int wv_id = tid >> 6;
    unsigned lane = tid & 63;
    float bj = bias[lane];
    __syncthreads();                   // wt staged (only barrier)

    const int* outi = (const int*)out;   // ELL aliased in out
    int ngroups = (n + 3) >> 2, gs = gridDim.x;
    int g = blockIdx.x;
    int d = g * 4 + wv_id;
    int ev = 0, mc = 0; float wvv = 0.f;
    if (d < n) {
        mc = degc[d];
        int e0 = outi[(unsigned)d * NF + lane];
        int m = min(mc, NF);
        ev = ((int)lane < m) ? e0 : 0;
        wvv = ((int)lane < m) ? dinv[ev] : 0.f;
    }
    while (g < ngroups) {
        int gn = g + gs, dn = gn * 4 + wv_id;
        int evn = 0, mcn = 0; float wvn = 0.f;
        if (gn < ngroups && dn < n) {          // prefetch next iteration
            mcn = degc[dn];
            int e0 = outi[(unsigned)dn * NF + lane];
            int mn = min(mcn, NF);
            evn = ((int)lane < mn) ? e0 : 0;
            wvn = ((int)lane < mn) ? dinv[evn] : 0.f;
        }
        if (d < n) {
            float dd = rsqrtf((float)(mc + 1));
            int m = min(mc, NF);
            float a0 = __half2float(xh[(unsigned)d * NF + lane]) * dd;   // self term
            float a1 = 0.f, a2 = 0.f, a3 = 0.f, a4 = 0.f, a5 = 0.f, a6 = 0.f, a7 = 0.f;
            for (int j = 0; j < m; j += 8) {   // mask-free: w=0 kills invalid slots
                int s0 = __shfl(ev, j + 0), s1 = __shfl(ev, j + 1);
                int s2 = __shfl(ev, j + 2), s3 = __shfl(ev, j + 3);
                int s4 = __shfl(ev, j + 4), s5 = __shfl(ev, j + 5);
                int s6 = __shfl(ev, j + 6), s7 = __shfl(ev, j + 7);
                float w0 = __shfl(wvv, j + 0), w1 = __shfl(wvv, j + 1);
                float w2 = __shfl(wvv, j + 2), w3 = __shfl(wvv, j + 3);
                float w4 = __shfl(wvv, j + 4), w5 = __shfl(wvv, j + 5);
                float w6 = __shfl(wvv, j + 6), w7 = __shfl(wvv, j + 7);
                a0 = fmaf(__half2float(xh[(unsigned)s0 * NF + lane]), w0, a0);
                a1 = fmaf(__half2float(xh[(unsigned)s1 * NF + lane]), w1, a1);
                a2 = fmaf(__half2float(xh[(unsigned)s2 * NF + lane]), w2, a2);
                a3 = fmaf(__half2float(xh[(unsigned)s3 * NF + lane]), w3, a3);
                a4 = fmaf(__half2float(xh[(unsigned)s4 * NF + lane]), w4, a4);
                a5 = fmaf(__half2float(xh[(unsigned)s5 * NF + lane]), w5, a5);
                a6 = fmaf(__half2float(xh[(unsigned)s6 * NF + lane]), w6, a6);
                a7 = fmaf(__half2float(xh[(unsigned)s7 * NF + lane]), w7, a7);
            }
            float v = dd * (((a0 + a1) + (a2 + a3)) + ((a4 + a5) + (a6 + a7)));

            vsh[wv_id][lane] = v;              // wave-local exchange, no barrier
            float r = bj;
#pragma unroll
            for (int k0 = 0; k0 < NF; k0 += 4) {
                float4 bv = *reinterpret_cast<const float4*>(&vsh[wv_id][k0]);  // broadcast
                r = fmaf(bv.x, wt[(k0 + 0) * NF + lane], r);
                r = fmaf(bv.y, wt[(k0 + 1) * NF + lane], r);
                r = fmaf(bv.z, wt[(k0 + 2) * NF + lane], r);
                r = fmaf(bv.w, wt[(k0 + 3) * NF + lane], r);
            }
            out[(unsigned)d * NF + lane] = r;
        }
        g = gn; d = dn; ev = evn; mc = mcn; wvv = wvn;
    }
}

// ---------------- overflow fixup (post-GEMM, by linearity) ----------------
__global__ __launch_bounds__(64) void k_oflow(const float* __restrict__ x,
                                              const float* __restrict__ W,
                                              const float* __restrict__ dinv,
                                              const int* __restrict__ ocnt,
                                              const int* __restrict__ oflow,
                                              float* out) {
    int c = *ocnt; if (c > OCAP) c = OCAP;
    int lane = threadIdx.x;
    for (int o = blockIdx.x; o < c; o += gridDim.x) {
        int s = oflow[2 * o], d = oflow[2 * o + 1];
        float norm = dinv[s] * dinv[d];
        float r = 0.f;
        for (int k = 0; k < NF; ++k)
            r = fmaf(x[(long)s * NF + k], W[lane * NF + k], r);
        atomicAdd(&out[(long)d * NF + lane], norm * r);
    }
}

// ---------------- launch ----------------

extern "C" void kernel_launch(void* const* d_in, const int* in_sizes, int n_in,
                              void* d_out, int out_size, void* d_ws, size_t ws_size,
                              hipStream_t stream) {
    const float* x    = (const float*)d_in[0];
    const int*   ei   = (const int*)d_in[1];   // harness pushes integers as int32
    const float* W    = (const float*)d_in[2];
    const float* bias = (const float*)d_in[3];
    float*       out  = (float*)d_out;

    const int n = in_sizes[0] / NF;       // 100000
    const int e = in_sizes[1] / 2;        // 1250000
    const int* src = ei;
    const int* dst = ei + e;

    // ws layout (~14.1MB): xh n*64 halfs | degc n | ocnt 1 | dinv n | oflow 2*OCAP
    __half* xh   = (__half*)d_ws;
    int*   degc  = (int*)(xh + (size_t)n * NF);
    int*   ocnt  = degc + n;
    float* dinv  = (float*)(ocnt + 1);
    int*   oflow = (int*)(dinv + n);

    dim3 blk(256);
    hipMemsetAsync(degc, 0, (size_t)(n + 1) * sizeof(int), stream);  // degc + ocnt
    int total4 = n * (NF / 4);
    k_half<<<(total4 + 255) / 256, blk, 0, stream>>>(x, xh, total4);
    k_ell <<<2048, blk, 0, stream>>>(src, dst, degc, ocnt, oflow, (int*)out, e, n);
    k_dinv<<<(n + 255) / 256, blk, 0, stream>>>(degc, dinv, n);
    k_agg_gemm<<<2048, blk, 0, stream>>>(xh, W, bias, dinv, degc, out, n);
    k_oflow<<<64, 64, 0, stream>>>(x, W, dinv, ocnt, oflow, out);
}